// Round 8
// baseline (554.668 us; speedup 1.0000x reference)
//
#include <hip/hip_runtime.h>

#define HH 192
#define WW 192
#define CC 128
#define BB 8
#define HW (HH * WW)          // 36864
#define OC 8
#define NPIX (BB * HW)        // 294912 per BN channel
#define YCHUNK (OC * BB * HW) // elements per y buffer
#define X0ROW 24576           // elems per (b,row): 2par*6ut*2048
#define X1ROW 28672           // elems per (b,row): 2par*7vt*2048

typedef __attribute__((ext_vector_type(8))) short bf16x8;
typedef __attribute__((ext_vector_type(4))) float f32x4;

__device__ __forceinline__ unsigned short f2bf(float f) {
    unsigned int u = __float_as_uint(f);
    u += 0x7fffu + ((u >> 16) & 1u);          // RNE
    return (unsigned short)(u >> 16);
}
__device__ __forceinline__ float bf2f(unsigned short u) {
    return __uint_as_float(((unsigned int)u) << 16);
}

// ---------------------------------------------------------------------------
// k_pack: fp32 [b][c][h][w] -> bf16 fragment-ordered tiles (unchanged r6/r7).
// x0t[b][i]: 12 tiles (par*6+ut) of 2048, tile=[q(4)][kg(4)][pxl(16)][e(8)].
// x1t[b][r]: 14 tiles (par*7+vt), v = 16*vt-8+pxl, zero outside [0,96).
// ---------------------------------------------------------------------------
__global__ __launch_bounds__(256) void k_pack(
    const float* __restrict__ x0, const float* __restrict__ x1,
    unsigned short* __restrict__ x0t, unsigned short* __restrict__ x1t)
{
    const int h = blockIdx.x, b = blockIdx.y, t = blockIdx.z;
    const float* src = t ? x1 : x0;
    __shared__ unsigned short lds[WW * 130];

    for (int idx = threadIdx.x; idx < CC * WW; idx += 256) {
        const int w = idx % WW, c = idx / WW;      // consecutive w per lane
        lds[w * 130 + c] = f2bf(src[((size_t)(b * CC + c) * HH + h) * WW + w]);
    }
    __syncthreads();

    if (t == 0) {
        unsigned int* dst = (unsigned int*)(x0t + (size_t)(b * HH + h) * X0ROW);
        for (int f2 = threadIdx.x; f2 < X0ROW / 2; f2 += 256) {
            const int e2  = f2 & 3;
            const int pxl = (f2 >> 2) & 15;
            const int kg  = (f2 >> 6) & 3;
            const int q   = (f2 >> 8) & 3;
            const int pu  = f2 >> 10;              // par*6 + ut
            const int ut  = pu % 6, par = pu / 6;
            const int px  = 2 * (16 * ut + pxl) + par;
            const int c   = q * 32 + kg * 8 + e2 * 2;
            const unsigned int lo = lds[px * 130 + c];
            const unsigned int hi = lds[px * 130 + c + 1];
            dst[f2] = lo | (hi << 16);
        }
    } else {
        unsigned int* dst = (unsigned int*)(x1t + (size_t)(b * HH + h) * X1ROW);
        for (int f2 = threadIdx.x; f2 < X1ROW / 2; f2 += 256) {
            const int e2  = f2 & 3;
            const int pxl = (f2 >> 2) & 15;
            const int kg  = (f2 >> 6) & 3;
            const int q   = (f2 >> 8) & 3;
            const int pv  = f2 >> 10;              // par*7 + vt
            const int vt  = pv % 7, par = pv / 7;
            const int v   = 16 * vt - 8 + pxl;
            unsigned int val = 0;
            if (v >= 0 && v < 96) {
                const int px = 2 * v + par;
                const int c  = q * 32 + kg * 8 + e2 * 2;
                val = lds[px * 130 + c] | ((unsigned int)lds[px * 130 + c + 1] << 16);
            }
            dst[f2] = val;
        }
    }
}

// ---------------------------------------------------------------------------
// K1-MFMA v8: pi-PAIRING. Per phase, two pi values share the A fragments
// (A-issued traffic halves); B row r at (pi,ir) == row at (pi+1,ir-2) ->
// hot in L1/L2 across ir steps. corr = 2 bf16 slabs [2][8][194][11] (68 KB,
// 2 blocks/CU). No tight VGPR bound: LDS caps residency, let loads pipeline.
// ---------------------------------------------------------------------------
__global__ __launch_bounds__(384) void k_corr_mfma_conv(
    const unsigned short* __restrict__ x0t, const unsigned short* __restrict__ x1t,
    const float* __restrict__ cw, const float* __restrict__ cb,
    float* __restrict__ y0, float* __restrict__ y1)
{
    const int L = blockIdx.x;                     // 512 blocks
    const int w = (L & 7) * 64 + (L >> 3);        // bijective XCD swizzle (512=8*64)
    const int b     = w >> 6;                     // image b pinned to XCD b
    const int rem   = w & 63;
    const int part  = rem >> 5;                   // 0..1
    const int strip = rem & 31;
    const int i0    = strip * 6;
    const int plo   = part ? 6 : 0;
    const int phi   = part ? 11 : 6;

    const int tid  = threadIdx.x;
    const int wave = tid >> 6, lane = tid & 63;
    const int ln15 = lane & 15, kg = lane >> 4;
    const int u0   = wave * 16;

    __shared__ unsigned short corr[2][8][194][11]; // bf16; jj=col+1; cols 0,193 zero

    if (tid < 352) {                               // zero pad columns of both slabs
        const int sl = tid / 176, r2 = tid % 176;
        const int ir = r2 / 22, rr = r2 % 22;
        const int pj = rr % 11, jj = (rr < 11) ? 0 : 193;
        corr[sl][ir][jj][pj] = 0;
    }

    float yacc[3][OC];
#pragma unroll
    for (int k = 0; k < 3; ++k)
#pragma unroll
        for (int o = 0; o < OC; ++o) yacc[k][o] = 0.f;

    const int jt  = tid % 192;                     // conv: column
    const int irb = tid / 192;                     // conv: rows irb, irb+2, irb+4

    const unsigned short* x0b = x0t + (size_t)b * HH * X0ROW;
    const unsigned short* x1b = x1t + (size_t)b * HH * X1ROW;

    for (int p0 = plo; p0 < phi; p0 += 2) {
        const int npair = (p0 + 1 < phi) ? 2 : 1;  // block-uniform
        __syncthreads();                           // conv done with corr slabs

        // ---------- MFMA band-GEMM: A loaded once per (ir,par), 2 pi ----------
        for (int ir = 0; ir < 8; ++ir) {
            const int i   = i0 - 1 + ir;
            const bool iv = (i >= 0) && (i < HH);
            const int icl = min(max(i, 0), HH - 1);
            const unsigned short* arow = x0b + (size_t)icl * X0ROW + lane * 8;

#pragma unroll
            for (int par = 0; par < 2; ++par) {
                const unsigned short* pa = arow + (par * 6 + wave) * 2048;
                const bf16x8 a0 = *(const bf16x8*)(pa);
                const bf16x8 a1 = *(const bf16x8*)(pa + 512);
                const bf16x8 a2 = *(const bf16x8*)(pa + 1024);
                const bf16x8 a3 = *(const bf16x8*)(pa + 1536);

#pragma unroll
                for (int p2 = 0; p2 < 2; ++p2) {
                    if (p2 < npair) {
                        const int pi = p0 + p2;
                        const int r  = i + 2 * pi - 10;
                        const bool gv = iv && (r >= 0) && (r < HH);
                        const int rcl = min(max(r, 0), HH - 1);
                        const unsigned short* brow =
                            x1b + (size_t)rcl * X1ROW + lane * 8;

#pragma unroll
                        for (int vtl = 0; vtl < 2; ++vtl) {
                            const unsigned short* pb =
                                brow + (par * 7 + wave + vtl) * 2048;
                            const bf16x8 b0 = *(const bf16x8*)(pb);
                            const bf16x8 b1 = *(const bf16x8*)(pb + 512);
                            const bf16x8 b2 = *(const bf16x8*)(pb + 1024);
                            const bf16x8 b3 = *(const bf16x8*)(pb + 1536);

                            f32x4 c = {0.f, 0.f, 0.f, 0.f};
                            c = __builtin_amdgcn_mfma_f32_16x16x32_bf16(a0, b0, c, 0, 0, 0);
                            c = __builtin_amdgcn_mfma_f32_16x16x32_bf16(a1, b1, c, 0, 0, 0);
                            c = __builtin_amdgcn_mfma_f32_16x16x32_bf16(a2, b2, c, 0, 0, 0);
                            c = __builtin_amdgcn_mfma_f32_16x16x32_bf16(a3, b3, c, 0, 0, 0);

                            const int v = u0 - 8 + 16 * vtl + ln15;
#pragma unroll
                            for (int rg = 0; rg < 4; ++rg) {
                                const int u  = u0 + kg * 4 + rg;
                                const int pj = v - u + 5;
                                if (pj >= 0 && pj < 11)
                                    corr[p2][ir][2 * u + par + 1][pj] =
                                        f2bf(gv ? c[rg] : 0.f);
                            }
                        }
                    }
                }
            }
        }
        __syncthreads();                           // both corr slabs visible

        // ---------- conv(3x3, 121->8), 3 px/thread, both pi slabs ----------
#pragma unroll
        for (int p2 = 0; p2 < 2; ++p2) {
            if (p2 < npair) {
                const int pi = p0 + p2;
                for (int ki = 0; ki < 3; ++ki) {
                    for (int kj = 0; kj < 3; ++kj) {
                        float cv[3][11];
#pragma unroll
                        for (int k = 0; k < 3; ++k) {
                            const unsigned short* cp =
                                &corr[p2][irb + 2 * k + ki][jt + kj][0];
#pragma unroll
                            for (int pj = 0; pj < 11; ++pj) cv[k][pj] = bf2f(cp[pj]);
                        }
#pragma unroll
                        for (int o = 0; o < OC; ++o) {
                            float a0 = yacc[0][o], a1 = yacc[1][o], a2 = yacc[2][o];
#pragma unroll
                            for (int pj = 0; pj < 11; ++pj) {
                                const float wv =       // wave-uniform -> s_load
                                    cw[o * 1089 + (pi * 11 + pj) * 9 + ki * 3 + kj];
                                a0 = fmaf(wv, cv[0][pj], a0);
                                a1 = fmaf(wv, cv[1][pj], a1);
                                a2 = fmaf(wv, cv[2][pj], a2);
                            }
                            yacc[0][o] = a0; yacc[1][o] = a1; yacc[2][o] = a2;
                        }
                    }
                }
            }
        }
    }

    float* yp = part ? y1 : y0;
#pragma unroll
    for (int k = 0; k < 3; ++k) {
        const int irow = i0 + irb + 2 * k;
#pragma unroll
        for (int o = 0; o < OC; ++o) {
            float val = yacc[k][o];
            if (part == 0) val += cb[o];
            yp[((size_t)(b * OC + o) * HH + irow) * WW + jt] = val;
        }
    }
}

// ---------------------------------------------------------------------------
// Fallback K1 (round-1 verified fp32 path) — only if ws too small
// ---------------------------------------------------------------------------
__global__ __launch_bounds__(256) void k_corr_conv(
    const float* __restrict__ x0, const float* __restrict__ x1,
    const float* __restrict__ cw, const float* __restrict__ cb,
    float* __restrict__ y)
{
    const int b  = blockIdx.z;
    const int i0 = blockIdx.y * 14;
    const int j0 = blockIdx.x * 14;
    const int li = threadIdx.x >> 4;
    const int lj = threadIdx.x & 15;
    const int gi = i0 + li - 1;
    const int gj = j0 + lj - 1;
    const bool valid    = (gi >= 0) & (gi < HH) & (gj >= 0) & (gj < WW);
    const bool interior = (li >= 1) & (li <= 14) & (lj >= 1) & (lj <= 14)
                        & (gi < HH) & (gj < WW);

    __shared__ float corr[16][16][13];

    float yacc[OC];
#pragma unroll
    for (int o = 0; o < OC; ++o) yacc[o] = 0.f;

    const size_t bbase = (size_t)b * CC * HW;
    const float* x0p = x0 + bbase + (size_t)gi * WW + gj;

    for (int pi = 0; pi < 11; ++pi) {
        float acc[11];
#pragma unroll
        for (int k = 0; k < 11; ++k) acc[k] = 0.f;

        const int r = gi + 2 * pi - 10;
        if (valid && r >= 0 && r < HH) {
            const float* p0 = x0p;
            if (gj >= 10 && gj <= WW - 11) {
                const float* p1o = x1 + bbase + (size_t)r * WW + (gj - 10);
#pragma unroll 2
                for (int c = 0; c < CC; ++c) {
                    const float a = *p0;
#pragma unroll
                    for (int k = 0; k < 11; ++k)
                        acc[k] = fmaf(a, p1o[2 * k], acc[k]);
                    p0 += HW; p1o += HW;
                }
            } else {
                const float* p1 = x1 + bbase + (size_t)r * WW;
#pragma unroll 2
                for (int c = 0; c < CC; ++c) {
                    const float a = *p0;
#pragma unroll
                    for (int k = 0; k < 11; ++k) {
                        const int col = gj + 2 * k - 10;
                        const float v = (col >= 0 && col < WW) ? p1[col] : 0.f;
                        acc[k] = fmaf(a, v, acc[k]);
                    }
                    p0 += HW; p1 += HW;
                }
            }
        }

        __syncthreads();
#pragma unroll
        for (int k = 0; k < 11; ++k) corr[li][lj][k] = acc[k];
        __syncthreads();

        if (interior) {
#pragma unroll
            for (int ki = 0; ki < 3; ++ki) {
#pragma unroll
                for (int kj = 0; kj < 3; ++kj) {
                    float cv[11];
#pragma unroll
                    for (int k = 0; k < 11; ++k)
                        cv[k] = corr[li + ki - 1][lj + kj - 1][k];
#pragma unroll
                    for (int o = 0; o < OC; ++o) {
#pragma unroll
                        for (int k = 0; k < 11; ++k) {
                            const float wv =
                                cw[(((o * 121) + pi * 11 + k) * 3 + ki) * 3 + kj];
                            yacc[o] = fmaf(wv, cv[k], yacc[o]);
                        }
                    }
                }
            }
        }
    }

    if (interior) {
#pragma unroll
        for (int o = 0; o < OC; ++o)
            y[(size_t)(b * OC + o) * HW + (size_t)gi * WW + gj] = yacc[o] + cb[o];
    }
}

// ---------------------------------------------------------------------------
// BN stats over up to 3 partial-y buffers (deterministic two-stage)
// ---------------------------------------------------------------------------
__global__ __launch_bounds__(256) void k_stats_partial(
    const float* __restrict__ y0, const float* __restrict__ y1,
    const float* __restrict__ y2, int n, float* __restrict__ st)
{
    const int bid = blockIdx.x;            // b*32 + o*4 + q
    const int b = bid >> 5, rem = bid & 31;
    const int o = rem >> 2, q = rem & 3;
    const size_t off = (size_t)(b * OC + o) * (HW / 4) + q * (HW / 16);
    const float4* p0 = (const float4*)y0 + off;
    const float4* p1 = (const float4*)y1 + off;
    const float4* p2 = (const float4*)y2 + off;
    float s = 0.f, qq = 0.f;
    for (int t = threadIdx.x; t < HW / 16; t += 256) {
        float4 z = p0[t];
        if (n >= 2) {
            const float4 v = p1[t];
            z.x += v.x; z.y += v.y; z.z += v.z; z.w += v.w;
        }
        if (n >= 3) {
            const float4 v = p2[t];
            z.x += v.x; z.y += v.y; z.z += v.z; z.w += v.w;
        }
        s += z.x + z.y + z.z + z.w;
        qq = fmaf(z.x, z.x, qq); qq = fmaf(z.y, z.y, qq);
        qq = fmaf(z.z, z.z, qq); qq = fmaf(z.w, z.w, qq);
    }
#pragma unroll
    for (int off2 = 32; off2 > 0; off2 >>= 1) {
        s  += __shfl_down(s, off2);
        qq += __shfl_down(qq, off2);
    }
    __shared__ float ss[4], sq[4];
    const int lane = threadIdx.x & 63, wv = threadIdx.x >> 6;
    if (lane == 0) { ss[wv] = s; sq[wv] = qq; }
    __syncthreads();
    if (threadIdx.x == 0) {
        st[bid]       = ss[0] + ss[1] + ss[2] + ss[3];
        st[256 + bid] = sq[0] + sq[1] + sq[2] + sq[3];
    }
}

__global__ void k_stats_final(float* __restrict__ st,
                              const float* __restrict__ gamma,
                              const float* __restrict__ beta)
{
    const int o = threadIdx.x;
    if (o < 8) {
        float S = 0.f, Q = 0.f;
#pragma unroll
        for (int b = 0; b < 8; ++b)
#pragma unroll
            for (int q = 0; q < 4; ++q) {
                S += st[b * 32 + o * 4 + q];
                Q += st[256 + b * 32 + o * 4 + q];
            }
        const float invN = 1.f / (float)NPIX;
        const float mean = S * invN;
        const float var  = Q * invN - mean * mean;
        const float sc   = gamma[o] / sqrtf(var + 1e-5f);
        st[512 + o] = sc;
        st[520 + o] = beta[o] - mean * sc;
    }
}

__global__ __launch_bounds__(256) void k_bn_relu(
    const float* __restrict__ y0, const float* __restrict__ y1,
    const float* __restrict__ y2, int n,
    const float* __restrict__ st, float* __restrict__ out)
{
    const int i = blockIdx.x * 256 + threadIdx.x;  // float4 idx, exact grid
    const int o = (i / (HW / 4)) & 7;
    const float sc = st[512 + o], sh = st[520 + o];
    float4 z = ((const float4*)y0)[i];
    if (n >= 2) {
        const float4 v = ((const float4*)y1)[i];
        z.x += v.x; z.y += v.y; z.z += v.z; z.w += v.w;
    }
    if (n >= 3) {
        const float4 v = ((const float4*)y2)[i];
        z.x += v.x; z.y += v.y; z.z += v.z; z.w += v.w;
    }
    float4 r;
    r.x = fmaxf(fmaf(z.x, sc, sh), 0.f);
    r.y = fmaxf(fmaf(z.y, sc, sh), 0.f);
    r.z = fmaxf(fmaf(z.z, sc, sh), 0.f);
    r.w = fmaxf(fmaf(z.w, sc, sh), 0.f);
    ((float4*)out)[i] = r;
}

extern "C" void kernel_launch(void* const* d_in, const int* in_sizes, int n_in,
                              void* d_out, int out_size, void* d_ws, size_t ws_size,
                              hipStream_t stream)
{
    const float* x0    = (const float*)d_in[0];
    const float* x1    = (const float*)d_in[1];
    const float* cw    = (const float*)d_in[2];
    const float* cb    = (const float*)d_in[3];
    const float* gamma = (const float*)d_in[4];
    const float* beta  = (const float*)d_in[5];
    float* out = (float*)d_out;
    float* st  = (float*)d_ws;   // stats scratch reuses ws base (x0t dead by then)

    const size_t x0bytes = (size_t)BB * HH * X0ROW * sizeof(unsigned short); // 72 MiB
    const size_t x1bytes = (size_t)BB * HH * X1ROW * sizeof(unsigned short); // 84 MiB
    const size_t ybytes  = (size_t)YCHUNK * sizeof(float);                   //  9 MiB

    if (ws_size >= x0bytes + x1bytes + ybytes) {
        unsigned short* x0t = (unsigned short*)d_ws;
        unsigned short* x1t = (unsigned short*)((char*)d_ws + x0bytes);
        float* y1           = (float*)((char*)d_ws + x0bytes + x1bytes);

        k_pack<<<dim3(HH, BB, 2), 256, 0, stream>>>(x0, x1, x0t, x1t);
        k_corr_mfma_conv<<<512, 384, 0, stream>>>(x0t, x1t, cw, cb, out, y1);
        k_stats_partial<<<256, 256, 0, stream>>>(out, y1, y1, 2, st);
        k_stats_final<<<1, 64, 0, stream>>>(st, gamma, beta);
        k_bn_relu<<<(YCHUNK / 4) / 256, 256, 0, stream>>>(out, y1, y1, 2, st, out);
    } else {
        dim3 g1(14, 14, 8);
        k_corr_conv<<<g1, 256, 0, stream>>>(x0, x1, cw, cb, out);
        k_stats_partial<<<256, 256, 0, stream>>>(out, out, out, 1, st);
        k_stats_final<<<1, 64, 0, stream>>>(st, gamma, beta);
        k_bn_relu<<<(YCHUNK / 4) / 256, 256, 0, stream>>>(out, out, out, 1, st, out);
    }
}